// Round 1
// baseline (3424.073 us; speedup 1.0000x reference)
//
#include <hip/hip_runtime.h>
#include <math.h>

// Problem constants
#define HH 200
#define WW 200
#define CIN 256
#define OMCH 108   // 72 offset + 36 mask
#define OCH 256
#define NPIX (HH*WW)

// ---------------------------------------------------------------------------
// K0a: transpose w_om [108][256][3][3] -> womt[c*9+tap][128] (padded cols)
__global__ void transpose_wom(const float* __restrict__ w_om, float* __restrict__ womt) {
    int i = blockIdx.x * 256 + threadIdx.x;   // i < 2304*128
    int ck = i >> 7, t = i & 127;
    womt[i] = (t < OMCH) ? w_om[t * 2304 + ck] : 0.f;
}

// K0b: transpose w_dcn [256][256][3][3] -> wdcnt[(gk*64+c)][256], gk=g*9+k
__global__ void transpose_wdcn(const float* __restrict__ w, float* __restrict__ wt) {
    int i = blockIdx.x * 256 + threadIdx.x;   // i < 2304*256
    int r = i >> 8, oc = i & 255;
    int c = r & 63, gk = r >> 6;
    int g = gk / 9, k = gk % 9;
    wt[i] = w[oc * 2304 + (g * 64 + c) * 9 + k];
}

// ---------------------------------------------------------------------------
// K1: om conv. 3x3, pad 1, C=256 -> 108 channels, + bias (no activation).
// Block: 128 threads, lane = oc (t<108 active for store). Tile: 25 pixels on one row.
__global__ __launch_bounds__(128) void om_conv(const float* __restrict__ x,
                                               const float* __restrict__ womt,
                                               const float* __restrict__ bom,
                                               float* __restrict__ om) {
    int bx = blockIdx.x;               // 2*200*8 = 3200 blocks
    int b = bx / 1600; int rem = bx % 1600;
    int h = rem >> 3; int w0 = (rem & 7) * 25;
    int t = threadIdx.x;

    __shared__ float xs[8][3][28];     // 8-ch chunk, 3 rows, 27 cols (+1 pad)

    float acc[25];
#pragma unroll
    for (int p = 0; p < 25; p++) acc[p] = 0.f;

    const float* xb = x + (size_t)b * CIN * NPIX;

    for (int c0 = 0; c0 < CIN; c0 += 8) {
        __syncthreads();
        for (int i = t; i < 648; i += 128) {   // 8*3*27 loads
            int cc = i / 81; int r2 = i % 81;
            int rr = r2 / 27; int col = r2 % 27;
            int hh = h + rr - 1; int ww = w0 + col - 1;
            float v = 0.f;
            if (hh >= 0 && hh < HH && ww >= 0 && ww < WW)
                v = xb[(size_t)(c0 + cc) * NPIX + hh * WW + ww];
            xs[cc][rr][col] = v;
        }
        __syncthreads();
        for (int cc = 0; cc < 8; cc++) {
#pragma unroll
            for (int ki = 0; ki < 3; ki++) {
                float xr[28];
#pragma unroll
                for (int j = 0; j < 7; j++)
                    *(float4*)&xr[4 * j] = *(const float4*)&xs[cc][ki][4 * j];
                int ckb = (c0 + cc) * 9 + ki * 3;
                float wv0 = womt[(ckb + 0) * 128 + t];
                float wv1 = womt[(ckb + 1) * 128 + t];
                float wv2 = womt[(ckb + 2) * 128 + t];
#pragma unroll
                for (int p = 0; p < 25; p++)
                    acc[p] += wv0 * xr[p] + wv1 * xr[p + 1] + wv2 * xr[p + 2];
            }
        }
    }

    if (t < OMCH) {
        float bv = bom[t];
        float* o = om + ((size_t)b * OMCH + t) * NPIX + h * WW + w0;
#pragma unroll
        for (int p = 0; p < 25; p++) o[p] = acc[p] + bv;
    }
}

// ---------------------------------------------------------------------------
// K2: fused deformable conv: bilinear sampling + output GEMM + ReLU.
// Block: 256 threads, lane = oc. Tile: 20 pixels on one row.
__global__ __launch_bounds__(256) void dcn_kernel(const float* __restrict__ x,
                                                  const float* __restrict__ om,
                                                  const float* __restrict__ wt,
                                                  float* __restrict__ out) {
    int bx = blockIdx.x;               // 2*200*10 = 4000 blocks
    int b = bx / 2000; int rem = bx % 2000;
    int h = rem / 10; int w0 = (rem % 10) * 20;
    int t = threadIdx.x;

    __shared__ float4 prmW[720];       // 36 gk * 20 p : 4 corner weights (mask folded)
    __shared__ int4   prmI[720];       // 4 corner indices (clamped)
    __shared__ float  vlds[64 * 20];   // sampled v for one gk: [c][p]

    // ---- phase A: sampling params per (gk, pixel)
    const float* omb = om + (size_t)b * OMCH * NPIX;
    for (int s = t; s < 720; s += 256) {
        int gk = s / 20, p = s % 20;
        int g = gk / 9, k = gk % 9;
        int ki = k / 3, kj = k % 3;
        int pix = h * WW + (w0 + p);
        float dy = omb[(size_t)(g * 18 + 2 * k    ) * NPIX + pix];
        float dx = omb[(size_t)(g * 18 + 2 * k + 1) * NPIX + pix];
        float mr = omb[(size_t)(72 + g * 9 + k    ) * NPIX + pix];
        float m = 1.f / (1.f + expf(-mr));
        float py = (float)(h - 1 + ki) + dy;
        float px = (float)(w0 + p - 1 + kj) + dx;
        float fy = floorf(py), fx = floorf(px);
        float wy = py - fy, wx = px - fx;
        int y0 = (int)fy, x0 = (int)fx;
        int y1 = y0 + 1, x1 = x0 + 1;
        bool vy0 = (y0 >= 0) && (y0 < HH), vy1 = (y1 >= 0) && (y1 < HH);
        bool vx0 = (x0 >= 0) && (x0 < WW), vx1 = (x1 >= 0) && (x1 < WW);
        int cy0 = min(max(y0, 0), HH - 1), cy1 = min(max(y1, 0), HH - 1);
        int cx0 = min(max(x0, 0), WW - 1), cx1 = min(max(x1, 0), WW - 1);
        float4 w4;
        w4.x = (vy0 && vx0) ? (1.f - wy) * (1.f - wx) * m : 0.f;
        w4.y = (vy0 && vx1) ? (1.f - wy) * wx * m : 0.f;
        w4.z = (vy1 && vx0) ? wy * (1.f - wx) * m : 0.f;
        w4.w = (vy1 && vx1) ? wy * wx * m : 0.f;
        int4 i4;
        i4.x = cy0 * WW + cx0; i4.y = cy0 * WW + cx1;
        i4.z = cy1 * WW + cx0; i4.w = cy1 * WW + cx1;
        prmW[s] = w4;
        prmI[s] = i4;
    }
    __syncthreads();

    float acc[20];
#pragma unroll
    for (int p = 0; p < 20; p++) acc[p] = 0.f;

    int c = t >> 2, q = t & 3;         // sampler mapping: 64 channels x 4 pixel-phases

    for (int gk = 0; gk < 36; gk++) {
        // ---- phase B: sample v[c][p] for this gk
        int g = gk / 9;
        const float* xc = x + ((size_t)b * CIN + g * 64 + c) * NPIX;
#pragma unroll
        for (int i = 0; i < 5; i++) {
            int p = q + 4 * i;
            int s = gk * 20 + p;
            float4 w4 = prmW[s];
            int4 i4 = prmI[s];
            float v = w4.x * xc[i4.x] + w4.y * xc[i4.y] + w4.z * xc[i4.z] + w4.w * xc[i4.w];
            vlds[c * 20 + p] = v;
        }
        __syncthreads();

        // ---- phase C: out[p][t] += sum_c wt[gk*64+c][t] * v[c][p]
        const float* wr = wt + (size_t)(gk * 64) * 256 + t;
#pragma unroll 4
        for (int cc = 0; cc < 64; cc++) {
            float wv = wr[cc * 256];
            const float* vr = &vlds[cc * 20];
            float vv[20];
            *(float4*)&vv[0]  = *(const float4*)&vr[0];
            *(float4*)&vv[4]  = *(const float4*)&vr[4];
            *(float4*)&vv[8]  = *(const float4*)&vr[8];
            *(float4*)&vv[12] = *(const float4*)&vr[12];
            *(float4*)&vv[16] = *(const float4*)&vr[16];
#pragma unroll
            for (int p = 0; p < 20; p++) acc[p] += wv * vv[p];
        }
        __syncthreads();
    }

    float* o = out + ((size_t)b * OCH + t) * NPIX + h * WW + w0;
#pragma unroll
    for (int p = 0; p < 20; p++) o[p] = fmaxf(acc[p], 0.f);
}

// ---------------------------------------------------------------------------
extern "C" void kernel_launch(void* const* d_in, const int* in_sizes, int n_in,
                              void* d_out, int out_size, void* d_ws, size_t ws_size,
                              hipStream_t stream) {
    const float* x     = (const float*)d_in[0];
    const float* w_om  = (const float*)d_in[1];
    const float* b_om  = (const float*)d_in[2];
    const float* w_dcn = (const float*)d_in[3];
    float* out = (float*)d_out;

    // workspace layout
    float* om    = (float*)d_ws;                                  // 2*108*40000*4 = 34,560,000 B
    float* womt  = (float*)((char*)d_ws + 34560000);              // 2304*128*4   =  1,179,648 B
    float* wdcnt = (float*)((char*)d_ws + 34560000 + 1179648);    // 2304*256*4   =  2,359,296 B

    transpose_wom <<<1152, 256, 0, stream>>>(w_om, womt);
    transpose_wdcn<<<2304, 256, 0, stream>>>(w_dcn, wdcnt);
    om_conv       <<<3200, 128, 0, stream>>>(x, womt, b_om, om);
    dcn_kernel    <<<4000, 256, 0, stream>>>(x, om, wdcnt, out);
}

// Round 2
// 1838.380 us; speedup vs baseline: 1.8625x; 1.8625x over previous
//
#include <hip/hip_runtime.h>
#include <math.h>

// Problem constants
#define HH 200
#define WW 200
#define CIN 256
#define OMCH 108   // 72 offset + 36 mask
#define OCH 256
#define NPIX (HH*WW)

typedef __bf16 bf16x8 __attribute__((ext_vector_type(8)));
typedef float floatx4 __attribute__((ext_vector_type(4)));

// ---------------------------------------------------------------------------
// K0a: transpose w_om [108][256][3][3] -> womt[c*9+tap][128] (padded cols)
__global__ void transpose_wom(const float* __restrict__ w_om, float* __restrict__ womt) {
    int i = blockIdx.x * 256 + threadIdx.x;   // i < 2304*128
    int ck = i >> 7, t = i & 127;
    womt[i] = (t < OMCH) ? w_om[t * 2304 + ck] : 0.f;
}

// K0b: w_dcn [256][256][3][3] fp32 -> wt2 bf16 [oc][klin], klin = (g*9+k)*64 + c
__global__ void prep_wdcn(const float* __restrict__ w, unsigned short* __restrict__ wt2) {
    int i = blockIdx.x * 256 + threadIdx.x;   // i < 256*2304
    int oc = i / 2304, klin = i % 2304;
    int gk = klin >> 6, c = klin & 63;
    int g = gk / 9, kk = gk % 9;
    float v = w[(size_t)oc * 2304 + (g * 64 + c) * 9 + kk];
    __bf16 h = (__bf16)v;
    wt2[i] = __builtin_bit_cast(unsigned short, h);
}

// ---------------------------------------------------------------------------
// K1: om conv. 3x3, pad 1, C=256 -> 108 channels, + bias (no activation). fp32.
__global__ __launch_bounds__(128) void om_conv(const float* __restrict__ x,
                                               const float* __restrict__ womt,
                                               const float* __restrict__ bom,
                                               float* __restrict__ om) {
    int bx = blockIdx.x;               // 2*200*8 = 3200 blocks
    int b = bx / 1600; int rem = bx % 1600;
    int h = rem >> 3; int w0 = (rem & 7) * 25;
    int t = threadIdx.x;

    __shared__ float xs[8][3][28];

    float acc[25];
#pragma unroll
    for (int p = 0; p < 25; p++) acc[p] = 0.f;

    const float* xb = x + (size_t)b * CIN * NPIX;

    for (int c0 = 0; c0 < CIN; c0 += 8) {
        __syncthreads();
        for (int i = t; i < 648; i += 128) {
            int cc = i / 81; int r2 = i % 81;
            int rr = r2 / 27; int col = r2 % 27;
            int hh = h + rr - 1; int ww = w0 + col - 1;
            float v = 0.f;
            if (hh >= 0 && hh < HH && ww >= 0 && ww < WW)
                v = xb[(size_t)(c0 + cc) * NPIX + hh * WW + ww];
            xs[cc][rr][col] = v;
        }
        __syncthreads();
        for (int cc = 0; cc < 8; cc++) {
#pragma unroll
            for (int ki = 0; ki < 3; ki++) {
                float xr[28];
#pragma unroll
                for (int j = 0; j < 7; j++)
                    *(float4*)&xr[4 * j] = *(const float4*)&xs[cc][ki][4 * j];
                int ckb = (c0 + cc) * 9 + ki * 3;
                float wv0 = womt[(ckb + 0) * 128 + t];
                float wv1 = womt[(ckb + 1) * 128 + t];
                float wv2 = womt[(ckb + 2) * 128 + t];
#pragma unroll
                for (int p = 0; p < 25; p++)
                    acc[p] += wv0 * xr[p] + wv1 * xr[p + 1] + wv2 * xr[p + 2];
            }
        }
    }

    if (t < OMCH) {
        float bv = bom[t];
        float* o = om + ((size_t)b * OMCH + t) * NPIX + h * WW + w0;
#pragma unroll
        for (int p = 0; p < 25; p++) o[p] = acc[p] + bv;
    }
}

// ---------------------------------------------------------------------------
// K2: fused DCN with bf16 MFMA output GEMM.
// Block: 256 threads (4 waves), 32 pixels (flat over B*H*W).
// Wave w handles oc [64w, 64w+64). Per gk: sample v[64c][32p] -> LDS bf16,
// then 2 K-steps x (4 oc-tiles x 2 p-tiles) of mfma_f32_16x16x32_bf16.
__global__ __launch_bounds__(256) void dcn_mfma(const float* __restrict__ x,
                                                const float* __restrict__ om,
                                                const unsigned short* __restrict__ wt2,
                                                float* __restrict__ out) {
    __shared__ __align__(16) unsigned short vbuf[2][32][72]; // [p][c], +8 pad, 16B-aligned rows

    int t = threadIdx.x;
    int p = t & 31;              // pixel within tile (sampler mapping)
    int cphase = t >> 5;         // 0..7 -> channels cphase*8 .. +8
    int lane = t & 63, quad = lane >> 4, n16 = lane & 15, wv = t >> 6;

    int gp0 = blockIdx.x * 32;   // flat pixel base over 2*40000
    int b = gp0 / NPIX;          // blocks never straddle b (40000 % 32 == 0)
    int pix = gp0 + p - b * NPIX;
    int h = pix / WW, w = pix % WW;

    const float* omb = om + (size_t)b * OMCH * NPIX;
    const float* xb  = x + (size_t)b * CIN * NPIX;

    floatx4 acc[4][2];
#pragma unroll
    for (int i = 0; i < 4; i++)
#pragma unroll
        for (int j = 0; j < 2; j++)
            acc[i][j] = (floatx4){0.f, 0.f, 0.f, 0.f};

    for (int gk = 0; gk < 36; gk++) {
        int g = gk / 9, kk = gk % 9;
        int ki = kk / 3, kj = kk % 3;

        // --- sampling params for (gk, my pixel) ---
        float dy = omb[(size_t)(g * 18 + 2 * kk    ) * NPIX + pix];
        float dx = omb[(size_t)(g * 18 + 2 * kk + 1) * NPIX + pix];
        float mr = omb[(size_t)(72 + g * 9 + kk    ) * NPIX + pix];
        float m = 1.f / (1.f + __expf(-mr));
        float py = (float)(h - 1 + ki) + dy;
        float px = (float)(w - 1 + kj) + dx;
        float fy = floorf(py), fx = floorf(px);
        float wy = py - fy, wx = px - fx;
        int y0 = (int)fy, x0 = (int)fx, y1 = y0 + 1, x1 = x0 + 1;
        bool vy0 = (y0 >= 0) && (y0 < HH), vy1 = (y1 >= 0) && (y1 < HH);
        bool vx0 = (x0 >= 0) && (x0 < WW), vx1 = (x1 >= 0) && (x1 < WW);
        int cy0 = min(max(y0, 0), HH - 1), cy1 = min(max(y1, 0), HH - 1);
        int cx0 = min(max(x0, 0), WW - 1), cx1 = min(max(x1, 0), WW - 1);
        float w00 = (vy0 && vx0) ? (1.f - wy) * (1.f - wx) * m : 0.f;
        float w01 = (vy0 && vx1) ? (1.f - wy) * wx * m : 0.f;
        float w10 = (vy1 && vx0) ? wy * (1.f - wx) * m : 0.f;
        float w11 = (vy1 && vx1) ? wy * wx * m : 0.f;
        int i00 = cy0 * WW + cx0, i01 = cy0 * WW + cx1;
        int i10 = cy1 * WW + cx0, i11 = cy1 * WW + cx1;

        // --- sample 8 channels, pack bf16, one b128 LDS write ---
        const float* xp = xb + (size_t)(g * 64 + cphase * 8) * NPIX;
        union { unsigned short u[8]; float4 f; } pk;
#pragma unroll
        for (int i = 0; i < 8; i++) {
            float v = w00 * xp[i00] + w01 * xp[i01] + w10 * xp[i10] + w11 * xp[i11];
            __bf16 hb = (__bf16)v;
            pk.u[i] = __builtin_bit_cast(unsigned short, hb);
            xp += NPIX;
        }
        *(float4*)&vbuf[gk & 1][p][cphase * 8] = pk.f;
        __syncthreads();

        // --- MFMA: out[oc][p] += W[oc][k] * V[k][p], k = gk*64 + ks*32 + ... ---
        const unsigned short* wrow = wt2 + gk * 64;
#pragma unroll
        for (int ks = 0; ks < 2; ks++) {
            bf16x8 b0 = *(const bf16x8*)&vbuf[gk & 1][n16     ][ks * 32 + quad * 8];
            bf16x8 b1 = *(const bf16x8*)&vbuf[gk & 1][16 + n16][ks * 32 + quad * 8];
#pragma unroll
            for (int oct = 0; oct < 4; oct++) {
                int oc = wv * 64 + oct * 16 + n16;
                bf16x8 a = *(const bf16x8*)&wrow[(size_t)oc * 2304 + ks * 32 + quad * 8];
                acc[oct][0] = __builtin_amdgcn_mfma_f32_16x16x32_bf16(a, b0, acc[oct][0], 0, 0, 0);
                acc[oct][1] = __builtin_amdgcn_mfma_f32_16x16x32_bf16(a, b1, acc[oct][1], 0, 0, 0);
            }
        }
        // no trailing barrier needed: next write goes to the other buffer, and
        // the barrier before the NEXT mfma phase orders writes(gk+2) after reads(gk).
    }

    // --- epilogue: D layout col=lane&15 (pixel), row=quad*4+reg (oc) ---
#pragma unroll
    for (int oct = 0; oct < 4; oct++)
#pragma unroll
        for (int pt = 0; pt < 2; pt++) {
            int pcol = pt * 16 + n16;
            int gpix = gp0 + pcol - b * NPIX;
#pragma unroll
            for (int r = 0; r < 4; r++) {
                int oc = wv * 64 + oct * 16 + quad * 4 + r;
                out[((size_t)(b * OCH + oc)) * NPIX + gpix] = fmaxf(acc[oct][pt][r], 0.f);
            }
        }
}

// ---------------------------------------------------------------------------
extern "C" void kernel_launch(void* const* d_in, const int* in_sizes, int n_in,
                              void* d_out, int out_size, void* d_ws, size_t ws_size,
                              hipStream_t stream) {
    const float* x     = (const float*)d_in[0];
    const float* w_om  = (const float*)d_in[1];
    const float* b_om  = (const float*)d_in[2];
    const float* w_dcn = (const float*)d_in[3];
    float* out = (float*)d_out;

    // workspace layout
    float* om            = (float*)d_ws;                                 // 34,560,000 B
    float* womt          = (float*)((char*)d_ws + 34560000);             //  1,179,648 B
    unsigned short* wt2  = (unsigned short*)((char*)d_ws + 35739648);    //  1,179,648 B

    transpose_wom<<<1152, 256, 0, stream>>>(w_om, womt);
    prep_wdcn    <<<2304, 256, 0, stream>>>(w_dcn, wt2);
    om_conv      <<<3200, 128, 0, stream>>>(x, womt, b_om, om);
    dcn_mfma     <<<2500, 256, 0, stream>>>(x, om, wt2, out);
}

// Round 3
// 925.776 us; speedup vs baseline: 3.6986x; 1.9858x over previous
//
#include <hip/hip_runtime.h>
#include <math.h>

// Problem constants
#define HH 200
#define WW 200
#define CIN 256
#define OMCH 108   // 72 offset + 36 mask
#define OCH 256
#define NPIX (HH*WW)

typedef __bf16 bf16x8 __attribute__((ext_vector_type(8)));
typedef float floatx4 __attribute__((ext_vector_type(4)));

static __device__ __forceinline__ unsigned short bf16bits(float v) {
    __bf16 h = (__bf16)v;
    return __builtin_bit_cast(unsigned short, h);
}

// ---------------------------------------------------------------------------
// P0: x [B][C][HW] fp32 -> xT [B][HW][C] bf16.  64-pixel tiles, LDS transpose.
__global__ __launch_bounds__(256) void transpose_x(const float* __restrict__ x,
                                                   unsigned short* __restrict__ xT) {
    __shared__ __align__(16) unsigned short st[64][264];   // row pad: 2-way banks on writes
    int t = threadIdx.x;
    int blk = blockIdx.x;                 // 2 * 625
    int b = blk / 625, pix0 = (blk % 625) * 64;
    const float* xb = x + (size_t)b * CIN * NPIX + pix0;
    int p = t & 63, oct = t >> 6;

    for (int c32 = 0; c32 < CIN; c32 += 32) {
        int c = c32 + oct * 8;
        union { unsigned short u[8]; float4 f; } pk;
#pragma unroll
        for (int i = 0; i < 8; i++)
            pk.u[i] = bf16bits(xb[(size_t)(c + i) * NPIX + p]);
        *(float4*)&st[p][c] = pk.f;
    }
    __syncthreads();
    int p2 = t >> 2, qo = t & 3;
    unsigned short* dst = xT + ((size_t)b * NPIX + pix0 + p2) * CIN + qo * 64;
#pragma unroll
    for (int j = 0; j < 8; j++)
        *(float4*)(dst + j * 8) = *(const float4*)&st[p2][qo * 64 + j * 8];
}

// ---------------------------------------------------------------------------
// P1: w_om [108][256][3][3] fp32 -> wom2 bf16 [128 padded oc][klin], klin = tap*256 + c
__global__ void prep_wom(const float* __restrict__ w, unsigned short* __restrict__ wom2) {
    int i = blockIdx.x * 256 + threadIdx.x;   // i < 128*2304
    int oc = i / 2304, klin = i % 2304;
    int tap = klin >> 8, c = klin & 255;
    float v = (oc < OMCH) ? w[(size_t)oc * 2304 + c * 9 + tap] : 0.f;
    wom2[i] = bf16bits(v);
}

// P2: w_dcn [256][256][3][3] fp32 -> wt2 bf16 [oc][klin], klin = (g*9+k)*64 + c
__global__ void prep_wdcn(const float* __restrict__ w, unsigned short* __restrict__ wt2) {
    int i = blockIdx.x * 256 + threadIdx.x;   // i < 256*2304
    int oc = i / 2304, klin = i % 2304;
    int gk = klin >> 6, c = klin & 63;
    int g = gk / 9, kk = gk % 9;
    wt2[i] = bf16bits(w[(size_t)oc * 2304 + (g * 64 + c) * 9 + kk]);
}

// ---------------------------------------------------------------------------
// K1: om conv via bf16 MFMA. 256 threads, 64 pixels/block.
// Waves: (wv&1) -> oc half [0..63]/[64..127], (wv>>1) -> pixel half.
// K-loop: 9 taps x 8 chunks of 32 channels; v[32c][64p] staged in LDS from xT.
__global__ __launch_bounds__(256) void om_mfma(const unsigned short* __restrict__ xT,
                                               const unsigned short* __restrict__ wom2,
                                               const float* __restrict__ bom,
                                               float* __restrict__ om) {
    __shared__ __align__(16) unsigned short vbuf[2][64][40];  // [p][32c + 8 pad]

    int t = threadIdx.x;
    int p = t & 63;
    int cphase = t >> 6;                  // 0..3 -> channels cphase*8
    int lane = t & 63, quad = lane >> 4, n16 = lane & 15, wv = t >> 6;

    int gp0 = blockIdx.x * 64;            // 1250 blocks; 40000 % 64 == 0
    int b = gp0 / NPIX;
    int pix = gp0 + p - b * NPIX;
    int h = pix / WW, w = pix % WW;
    const unsigned short* xtb = xT + (size_t)b * NPIX * CIN;

    floatx4 acc[4][2];
#pragma unroll
    for (int i = 0; i < 4; i++)
#pragma unroll
        for (int j = 0; j < 2; j++) acc[i][j] = (floatx4){0.f, 0.f, 0.f, 0.f};

    int ocbase = (wv & 1) * 64;
    int ph = (wv >> 1) * 32;

    int it = 0;
    for (int tap = 0; tap < 9; tap++) {
        int di = tap / 3 - 1, dj = tap % 3 - 1;
        int h2 = h + di, w2 = w + dj;
        bool valid = ((unsigned)h2 < (unsigned)HH) && ((unsigned)w2 < (unsigned)WW);
        const unsigned short* xrow = xtb + (size_t)(valid ? (h2 * WW + w2) : 0) * CIN + cphase * 8;
        for (int c0 = 0; c0 < CIN; c0 += 32, it++) {
            float4 pk = {0.f, 0.f, 0.f, 0.f};
            if (valid) pk = *(const float4*)(xrow + c0);
            *(float4*)&vbuf[it & 1][p][cphase * 8] = pk;
            __syncthreads();

            const unsigned short* wr = wom2 + (size_t)(tap * 256 + c0) + quad * 8;
            bf16x8 b0 = *(const bf16x8*)&vbuf[it & 1][ph + n16     ][quad * 8];
            bf16x8 b1 = *(const bf16x8*)&vbuf[it & 1][ph + 16 + n16][quad * 8];
#pragma unroll
            for (int oct = 0; oct < 4; oct++) {
                int oc = ocbase + oct * 16 + n16;
                bf16x8 a = *(const bf16x8*)&wr[(size_t)oc * 2304];
                acc[oct][0] = __builtin_amdgcn_mfma_f32_16x16x32_bf16(a, b0, acc[oct][0], 0, 0, 0);
                acc[oct][1] = __builtin_amdgcn_mfma_f32_16x16x32_bf16(a, b1, acc[oct][1], 0, 0, 0);
            }
        }
    }

    // epilogue: D col = n16 (pixel), row = quad*4+r (oc); + bias, no activation
#pragma unroll
    for (int oct = 0; oct < 4; oct++) {
        int oc = ocbase + oct * 16 + quad * 4;
        if (oc < OMCH) {
#pragma unroll
            for (int pt = 0; pt < 2; pt++) {
                int pcol = ph + pt * 16 + n16;
                int gpix = gp0 - b * NPIX + pcol;
#pragma unroll
                for (int r = 0; r < 4; r++) {
                    int occ = oc + r;
                    if (occ < OMCH)
                        om[((size_t)(b * OMCH + occ)) * NPIX + gpix] = acc[oct][pt][r] + bom[occ];
                }
            }
        }
    }
}

// ---------------------------------------------------------------------------
// K2: fused DCN with bf16 MFMA output GEMM; bilinear gathers from xT (vectorized).
__global__ __launch_bounds__(256) void dcn_mfma(const unsigned short* __restrict__ xT,
                                                const float* __restrict__ om,
                                                const unsigned short* __restrict__ wt2,
                                                float* __restrict__ out) {
    __shared__ __align__(16) unsigned short vbuf[2][32][72]; // [p][64c + 8 pad]

    int t = threadIdx.x;
    int p = t & 31;              // pixel within tile
    int cphase = t >> 5;         // 0..7 -> channels cphase*8
    int lane = t & 63, quad = lane >> 4, n16 = lane & 15, wv = t >> 6;

    int gp0 = blockIdx.x * 32;   // 2500 blocks
    int b = gp0 / NPIX;
    int pix = gp0 + p - b * NPIX;
    int h = pix / WW, w = pix % WW;

    const float* omb = om + (size_t)b * OMCH * NPIX;
    const unsigned short* xtb = xT + (size_t)b * NPIX * CIN;

    floatx4 acc[4][2];
#pragma unroll
    for (int i = 0; i < 4; i++)
#pragma unroll
        for (int j = 0; j < 2; j++) acc[i][j] = (floatx4){0.f, 0.f, 0.f, 0.f};

    for (int gk = 0; gk < 36; gk++) {
        int g = gk / 9, kk = gk % 9;
        int ki = kk / 3, kj = kk % 3;

        // --- sampling params for (gk, my pixel) ---
        float dy = omb[(size_t)(g * 18 + 2 * kk    ) * NPIX + pix];
        float dx = omb[(size_t)(g * 18 + 2 * kk + 1) * NPIX + pix];
        float mr = omb[(size_t)(72 + g * 9 + kk    ) * NPIX + pix];
        float m = 1.f / (1.f + __expf(-mr));
        float py = (float)(h - 1 + ki) + dy;
        float px = (float)(w - 1 + kj) + dx;
        float fy = floorf(py), fx = floorf(px);
        float wy = py - fy, wx = px - fx;
        int y0 = (int)fy, x0 = (int)fx, y1 = y0 + 1, x1 = x0 + 1;
        bool vy0 = (y0 >= 0) && (y0 < HH), vy1 = (y1 >= 0) && (y1 < HH);
        bool vx0 = (x0 >= 0) && (x0 < WW), vx1 = (x1 >= 0) && (x1 < WW);
        int cy0 = min(max(y0, 0), HH - 1), cy1 = min(max(y1, 0), HH - 1);
        int cx0 = min(max(x0, 0), WW - 1), cx1 = min(max(x1, 0), WW - 1);
        float w00 = (vy0 && vx0) ? (1.f - wy) * (1.f - wx) * m : 0.f;
        float w01 = (vy0 && vx1) ? (1.f - wy) * wx * m : 0.f;
        float w10 = (vy1 && vx0) ? wy * (1.f - wx) * m : 0.f;
        float w11 = (vy1 && vx1) ? wy * wx * m : 0.f;

        // --- vectorized corner loads: 8 channels each, bf16 ---
        const unsigned short* xg = xtb + g * 64 + cphase * 8;
        bf16x8 c00 = *(const bf16x8*)(xg + (size_t)(cy0 * WW + cx0) * CIN);
        bf16x8 c01 = *(const bf16x8*)(xg + (size_t)(cy0 * WW + cx1) * CIN);
        bf16x8 c10 = *(const bf16x8*)(xg + (size_t)(cy1 * WW + cx0) * CIN);
        bf16x8 c11 = *(const bf16x8*)(xg + (size_t)(cy1 * WW + cx1) * CIN);

        union { unsigned short u[8]; float4 f; } pk;
#pragma unroll
        for (int i = 0; i < 8; i++) {
            float v = w00 * (float)c00[i] + w01 * (float)c01[i]
                    + w10 * (float)c10[i] + w11 * (float)c11[i];
            pk.u[i] = bf16bits(v);
        }
        *(float4*)&vbuf[gk & 1][p][cphase * 8] = pk.f;
        __syncthreads();

        // --- MFMA: out[oc][p] += W[oc][k] * V[k][p] ---
        const unsigned short* wrow = wt2 + gk * 64;
#pragma unroll
        for (int ks = 0; ks < 2; ks++) {
            bf16x8 b0 = *(const bf16x8*)&vbuf[gk & 1][n16     ][ks * 32 + quad * 8];
            bf16x8 b1 = *(const bf16x8*)&vbuf[gk & 1][16 + n16][ks * 32 + quad * 8];
#pragma unroll
            for (int oct = 0; oct < 4; oct++) {
                int oc = wv * 64 + oct * 16 + n16;
                bf16x8 a = *(const bf16x8*)&wrow[(size_t)oc * 2304 + ks * 32 + quad * 8];
                acc[oct][0] = __builtin_amdgcn_mfma_f32_16x16x32_bf16(a, b0, acc[oct][0], 0, 0, 0);
                acc[oct][1] = __builtin_amdgcn_mfma_f32_16x16x32_bf16(a, b1, acc[oct][1], 0, 0, 0);
            }
        }
    }

    // --- epilogue: D col = n16 (pixel), row = quad*4+reg (oc); ReLU ---
#pragma unroll
    for (int oct = 0; oct < 4; oct++)
#pragma unroll
        for (int pt = 0; pt < 2; pt++) {
            int pcol = pt * 16 + n16;
            int gpix = gp0 + pcol - b * NPIX;
#pragma unroll
            for (int r = 0; r < 4; r++) {
                int oc = wv * 64 + oct * 16 + quad * 4 + r;
                out[((size_t)(b * OCH + oc)) * NPIX + gpix] = fmaxf(acc[oct][pt][r], 0.f);
            }
        }
}

// ---------------------------------------------------------------------------
extern "C" void kernel_launch(void* const* d_in, const int* in_sizes, int n_in,
                              void* d_out, int out_size, void* d_ws, size_t ws_size,
                              hipStream_t stream) {
    const float* x     = (const float*)d_in[0];
    const float* w_om  = (const float*)d_in[1];
    const float* b_om  = (const float*)d_in[2];
    const float* w_dcn = (const float*)d_in[3];
    float* out = (float*)d_out;

    // workspace layout (77.3 MB total)
    char* ws = (char*)d_ws;
    float*          om   = (float*)(ws);                         // 34,560,000 B
    unsigned short* xT   = (unsigned short*)(ws + 34560000);     // 40,960,000 B
    unsigned short* wom2 = (unsigned short*)(ws + 75520000);     //    589,824 B
    unsigned short* wt2  = (unsigned short*)(ws + 76109824);     //  1,179,648 B

    transpose_x<<<1250, 256, 0, stream>>>(x, xT);
    prep_wom   <<<1152, 256, 0, stream>>>(w_om, wom2);
    prep_wdcn  <<<2304, 256, 0, stream>>>(w_dcn, wt2);
    om_mfma    <<<1250, 256, 0, stream>>>(xT, wom2, b_om, om);
    dcn_mfma   <<<2500, 256, 0, stream>>>(xT, om, wt2, out);
}

// Round 4
// 616.019 us; speedup vs baseline: 5.5584x; 1.5028x over previous
//
#include <hip/hip_runtime.h>
#include <math.h>

// Problem constants
#define HH 200
#define WW 200
#define CIN 256
#define OMCH 108   // 72 offset + 36 mask
#define OCH 256
#define NPIX (HH*WW)

typedef __bf16 bf16x8 __attribute__((ext_vector_type(8)));
typedef float floatx4 __attribute__((ext_vector_type(4)));

static __device__ __forceinline__ unsigned short bf16bits(float v) {
    __bf16 h = (__bf16)v;
    return __builtin_bit_cast(unsigned short, h);
}

// ---------------------------------------------------------------------------
// P0: x [B][C][HW] fp32 -> xT [B][HW][C] bf16.  64-pixel tiles, LDS transpose.
__global__ __launch_bounds__(256) void transpose_x(const float* __restrict__ x,
                                                   unsigned short* __restrict__ xT) {
    __shared__ __align__(16) unsigned short st[64][264];
    int t = threadIdx.x;
    int blk = blockIdx.x;                 // 2 * 625
    int b = blk / 625, pix0 = (blk % 625) * 64;
    const float* xb = x + (size_t)b * CIN * NPIX + pix0;
    int p = t & 63, oct = t >> 6;

    for (int c32 = 0; c32 < CIN; c32 += 32) {
        int c = c32 + oct * 8;
        union { unsigned short u[8]; float4 f; } pk;
#pragma unroll
        for (int i = 0; i < 8; i++)
            pk.u[i] = bf16bits(xb[(size_t)(c + i) * NPIX + p]);
        *(float4*)&st[p][c] = pk.f;
    }
    __syncthreads();
    int p2 = t >> 2, qo = t & 3;
    unsigned short* dst = xT + ((size_t)b * NPIX + pix0 + p2) * CIN + qo * 64;
#pragma unroll
    for (int j = 0; j < 8; j++)
        *(float4*)(dst + j * 8) = *(const float4*)&st[p2][qo * 64 + j * 8];
}

// ---------------------------------------------------------------------------
// P1: w_om [108][256][3][3] fp32 -> wom2 bf16 [128 padded oc][klin], klin = tap*256 + c
__global__ void prep_wom(const float* __restrict__ w, unsigned short* __restrict__ wom2) {
    int i = blockIdx.x * 256 + threadIdx.x;   // i < 128*2304
    int oc = i / 2304, klin = i % 2304;
    int tap = klin >> 8, c = klin & 255;
    float v = (oc < OMCH) ? w[(size_t)oc * 2304 + c * 9 + tap] : 0.f;
    wom2[i] = bf16bits(v);
}

// P2: w_dcn [256][256][3][3] fp32 -> wt2 bf16 [oc][klin], klin = (g*9+k)*64 + c
__global__ void prep_wdcn(const float* __restrict__ w, unsigned short* __restrict__ wt2) {
    int i = blockIdx.x * 256 + threadIdx.x;   // i < 256*2304
    int oc = i / 2304, klin = i % 2304;
    int gk = klin >> 6, c = klin & 63;
    int g = gk / 9, kk = gk % 9;
    wt2[i] = bf16bits(w[(size_t)oc * 2304 + (g * 64 + c) * 9 + kk]);
}

// ---------------------------------------------------------------------------
// K1: om conv via bf16 MFMA, software-pipelined staging.
// 256 thr / 4 waves, 64 px/block. Wave wv -> oc [32wv, 32wv+32).
// 36 iters: tap (9) x 64-ch chunk (4); per iter stage v[64c][64p] from xT.
__global__ __launch_bounds__(256, 4) void om_mfma(const unsigned short* __restrict__ xT,
                                                  const unsigned short* __restrict__ wom2,
                                                  const float* __restrict__ bom,
                                                  float* __restrict__ om) {
    __shared__ __align__(16) unsigned short vbuf[2][64][72];  // [p][64c + 8 pad]

    int t = threadIdx.x;
    int p = t & 63;                       // staging pixel (== lane)
    int coff = (t >> 6) * 16;             // staging channels [coff, coff+16)
    int n16 = t & 15, quad = (t & 63) >> 4, wv = t >> 6;
    int ocbase = wv * 32;

    int gp0 = blockIdx.x * 64;            // 1250 blocks
    int b = gp0 / NPIX;
    int pix0 = gp0 - b * NPIX;
    int pix = pix0 + p;
    int h = pix / WW, w = pix % WW;
    const unsigned short* xtb = xT + (size_t)b * NPIX * CIN;

    floatx4 acc[2][4];
#pragma unroll
    for (int i = 0; i < 2; i++)
#pragma unroll
        for (int j = 0; j < 4; j++) acc[i][j] = (floatx4){0.f, 0.f, 0.f, 0.f};

    // stage it=0 (tap 0: di=-1,dj=-1; c0=0)
    {
        int h2 = h - 1, w2 = w - 1;
        bool valid = ((unsigned)h2 < (unsigned)HH) && ((unsigned)w2 < (unsigned)WW);
        float4 fa = {0.f,0.f,0.f,0.f}, fb = {0.f,0.f,0.f,0.f};
        if (valid) {
            const unsigned short* src = xtb + (size_t)(h2 * WW + w2) * CIN + coff;
            fa = *(const float4*)src;
            fb = *(const float4*)(src + 8);
        }
        *(float4*)&vbuf[0][p][coff]     = fa;
        *(float4*)&vbuf[0][p][coff + 8] = fb;
    }
    __syncthreads();

    for (int it = 0; it < 36; it++) {
        int tap = it >> 2, c0 = (it & 3) << 6;
        int cur = it & 1;
        bool have = (it < 35);

        // --- prefetch next staging chunk into registers ---
        float4 nfa = {0.f,0.f,0.f,0.f}, nfb = {0.f,0.f,0.f,0.f};
        if (have) {
            int itn = it + 1;
            int tapn = itn >> 2, c0n = (itn & 3) << 6;
            int h2 = h + tapn / 3 - 1, w2 = w + tapn % 3 - 1;
            bool valid = ((unsigned)h2 < (unsigned)HH) && ((unsigned)w2 < (unsigned)WW);
            if (valid) {
                const unsigned short* src = xtb + (size_t)(h2 * WW + w2) * CIN + c0n + coff;
                nfa = *(const float4*)src;
                nfb = *(const float4*)(src + 8);
            }
        }

        // --- MFMA phase ---
        const unsigned short* wb = wom2 + (size_t)(tap * 256 + c0) + quad * 8;
#pragma unroll
        for (int ks = 0; ks < 2; ks++) {
            bf16x8 bf0 = *(const bf16x8*)&vbuf[cur][n16     ][ks * 32 + quad * 8];
            bf16x8 bf1 = *(const bf16x8*)&vbuf[cur][16 + n16][ks * 32 + quad * 8];
            bf16x8 bf2 = *(const bf16x8*)&vbuf[cur][32 + n16][ks * 32 + quad * 8];
            bf16x8 bf3 = *(const bf16x8*)&vbuf[cur][48 + n16][ks * 32 + quad * 8];
#pragma unroll
            for (int oi = 0; oi < 2; oi++) {
                bf16x8 a = *(const bf16x8*)&wb[(size_t)(ocbase + oi * 16 + n16) * 2304 + ks * 32];
                acc[oi][0] = __builtin_amdgcn_mfma_f32_16x16x32_bf16(a, bf0, acc[oi][0], 0, 0, 0);
                acc[oi][1] = __builtin_amdgcn_mfma_f32_16x16x32_bf16(a, bf1, acc[oi][1], 0, 0, 0);
                acc[oi][2] = __builtin_amdgcn_mfma_f32_16x16x32_bf16(a, bf2, acc[oi][2], 0, 0, 0);
                acc[oi][3] = __builtin_amdgcn_mfma_f32_16x16x32_bf16(a, bf3, acc[oi][3], 0, 0, 0);
            }
        }

        if (have) {
            *(float4*)&vbuf[cur ^ 1][p][coff]     = nfa;
            *(float4*)&vbuf[cur ^ 1][p][coff + 8] = nfb;
            __syncthreads();
        }
    }

    // epilogue: D col = n16 (pixel), row = quad*4+r (oc); + bias
#pragma unroll
    for (int oi = 0; oi < 2; oi++) {
        int oc0 = ocbase + oi * 16 + quad * 4;
#pragma unroll
        for (int pt = 0; pt < 4; pt++) {
            int gpix = pix0 + pt * 16 + n16;
#pragma unroll
            for (int r = 0; r < 4; r++) {
                int occ = oc0 + r;
                if (occ < OMCH)
                    om[((size_t)(b * OMCH + occ)) * NPIX + gpix] = acc[oi][pt][r] + bom[occ];
            }
        }
    }
}

// ---------------------------------------------------------------------------
// K2: fused DCN. 512 thr / 8 waves, 64 px/block. Wave wv -> oc [32wv, +32).
// Prologue: all 36x64 sampling param records -> LDS (coalesced om reads).
// Main loop: prefetch gk+1 corner gathers ahead of gk's MFMA phase.
__global__ __launch_bounds__(512, 4) void dcn_mfma(const unsigned short* __restrict__ xT,
                                                   const float* __restrict__ om,
                                                   const unsigned short* __restrict__ wt2,
                                                   float* __restrict__ out) {
    __shared__ float4  wPar[36 * 64];                        // 36864 B
    __shared__ ushort4 iPar[36 * 64];                        // 18432 B
    __shared__ __align__(16) unsigned short vbuf[2][64][72]; // 18432 B

    int t = threadIdx.x;
    int l = t & 63;               // lane = staging pixel
    int oct = t >> 6;             // staging octet == wave id
    int n16 = t & 15, quad = l >> 4;
    int ocbase = oct * 32;

    int gp0 = blockIdx.x * 64;    // 1250 blocks
    int b = gp0 / NPIX;
    int pix0 = gp0 - b * NPIX;
    const unsigned short* xtb = xT + (size_t)b * NPIX * CIN;
    const float* omb = om + (size_t)b * OMCH * NPIX;

    // ---- prologue: sampling params for all (gk, p) ----
    for (int r = t; r < 36 * 64; r += 512) {
        int gk = r >> 6, p = r & 63;
        int g = gk / 9, kk = gk % 9;
        int ki = kk / 3, kj = kk % 3;
        int pp = pix0 + p;
        int hh = pp / WW, ww2 = pp % WW;
        float dy = omb[(size_t)(g * 18 + 2 * kk    ) * NPIX + pp];
        float dx = omb[(size_t)(g * 18 + 2 * kk + 1) * NPIX + pp];
        float mr = omb[(size_t)(72 + g * 9 + kk    ) * NPIX + pp];
        float m = 1.f / (1.f + __expf(-mr));
        float py = (float)(hh - 1 + ki) + dy;
        float px = (float)(ww2 - 1 + kj) + dx;
        float fy = floorf(py), fx = floorf(px);
        float wy = py - fy, wx = px - fx;
        int y0 = (int)fy, x0 = (int)fx, y1 = y0 + 1, x1 = x0 + 1;
        bool vy0 = (y0 >= 0) && (y0 < HH), vy1 = (y1 >= 0) && (y1 < HH);
        bool vx0 = (x0 >= 0) && (x0 < WW), vx1 = (x1 >= 0) && (x1 < WW);
        int cy0 = min(max(y0, 0), HH - 1), cy1 = min(max(y1, 0), HH - 1);
        int cx0 = min(max(x0, 0), WW - 1), cx1 = min(max(x1, 0), WW - 1);
        float4 w4;
        w4.x = (vy0 && vx0) ? (1.f - wy) * (1.f - wx) * m : 0.f;
        w4.y = (vy0 && vx1) ? (1.f - wy) * wx * m : 0.f;
        w4.z = (vy1 && vx0) ? wy * (1.f - wx) * m : 0.f;
        w4.w = (vy1 && vx1) ? wy * wx * m : 0.f;
        ushort4 i4;
        i4.x = (unsigned short)(cy0 * WW + cx0);
        i4.y = (unsigned short)(cy0 * WW + cx1);
        i4.z = (unsigned short)(cy1 * WW + cx0);
        i4.w = (unsigned short)(cy1 * WW + cx1);
        wPar[r] = w4;
        iPar[r] = i4;
    }
    __syncthreads();

    floatx4 acc[2][4];
#pragma unroll
    for (int i = 0; i < 2; i++)
#pragma unroll
        for (int j = 0; j < 4; j++) acc[i][j] = (floatx4){0.f, 0.f, 0.f, 0.f};

    // ---- stage gk = 0 ----
    {
        float4 w4 = wPar[l];
        ushort4 i4 = iPar[l];
        const unsigned short* xg = xtb + oct * 8;       // g = 0
        bf16x8 c00 = *(const bf16x8*)(xg + (size_t)i4.x * CIN);
        bf16x8 c01 = *(const bf16x8*)(xg + (size_t)i4.y * CIN);
        bf16x8 c10 = *(const bf16x8*)(xg + (size_t)i4.z * CIN);
        bf16x8 c11 = *(const bf16x8*)(xg + (size_t)i4.w * CIN);
        union { unsigned short u[8]; float4 f; } pk;
#pragma unroll
        for (int i = 0; i < 8; i++) {
            float v = w4.x * (float)c00[i] + w4.y * (float)c01[i]
                    + w4.z * (float)c10[i] + w4.w * (float)c11[i];
            pk.u[i] = bf16bits(v);
        }
        *(float4*)&vbuf[0][l][oct * 8] = pk.f;
    }
    __syncthreads();

    for (int gk = 0; gk < 36; gk++) {
        int cur = gk & 1;
        bool have = (gk < 35);

        // --- prefetch gk+1 corner gathers ---
        float4 nw4;
        bf16x8 n00, n01, n10, n11;
        if (have) {
            int gkn = gk + 1;
            nw4 = wPar[gkn * 64 + l];
            ushort4 i4 = iPar[gkn * 64 + l];
            const unsigned short* xg = xtb + (gkn / 9) * 64 + oct * 8;
            n00 = *(const bf16x8*)(xg + (size_t)i4.x * CIN);
            n01 = *(const bf16x8*)(xg + (size_t)i4.y * CIN);
            n10 = *(const bf16x8*)(xg + (size_t)i4.z * CIN);
            n11 = *(const bf16x8*)(xg + (size_t)i4.w * CIN);
        }

        // --- MFMA phase ---
        const unsigned short* wb = wt2 + gk * 64 + quad * 8;
#pragma unroll
        for (int ks = 0; ks < 2; ks++) {
            bf16x8 bf0 = *(const bf16x8*)&vbuf[cur][n16     ][ks * 32 + quad * 8];
            bf16x8 bf1 = *(const bf16x8*)&vbuf[cur][16 + n16][ks * 32 + quad * 8];
            bf16x8 bf2 = *(const bf16x8*)&vbuf[cur][32 + n16][ks * 32 + quad * 8];
            bf16x8 bf3 = *(const bf16x8*)&vbuf[cur][48 + n16][ks * 32 + quad * 8];
#pragma unroll
            for (int oi = 0; oi < 2; oi++) {
                bf16x8 a = *(const bf16x8*)&wb[(size_t)(ocbase + oi * 16 + n16) * 2304 + ks * 32];
                acc[oi][0] = __builtin_amdgcn_mfma_f32_16x16x32_bf16(a, bf0, acc[oi][0], 0, 0, 0);
                acc[oi][1] = __builtin_amdgcn_mfma_f32_16x16x32_bf16(a, bf1, acc[oi][1], 0, 0, 0);
                acc[oi][2] = __builtin_amdgcn_mfma_f32_16x16x32_bf16(a, bf2, acc[oi][2], 0, 0, 0);
                acc[oi][3] = __builtin_amdgcn_mfma_f32_16x16x32_bf16(a, bf3, acc[oi][3], 0, 0, 0);
            }
        }

        if (have) {
            union { unsigned short u[8]; float4 f; } pk;
#pragma unroll
            for (int i = 0; i < 8; i++) {
                float v = nw4.x * (float)n00[i] + nw4.y * (float)n01[i]
                        + nw4.z * (float)n10[i] + nw4.w * (float)n11[i];
                pk.u[i] = bf16bits(v);
            }
            *(float4*)&vbuf[cur ^ 1][l][oct * 8] = pk.f;
            __syncthreads();
        }
    }

    // ---- epilogue: ReLU + store ----
#pragma unroll
    for (int oi = 0; oi < 2; oi++)
#pragma unroll
        for (int pt = 0; pt < 4; pt++) {
            int gpix = pix0 + pt * 16 + n16;
#pragma unroll
            for (int r = 0; r < 4; r++) {
                int oc = ocbase + oi * 16 + quad * 4 + r;
                out[((size_t)(b * OCH + oc)) * NPIX + gpix] = fmaxf(acc[oi][pt][r], 0.f);
            }
        }
}

// ---------------------------------------------------------------------------
extern "C" void kernel_launch(void* const* d_in, const int* in_sizes, int n_in,
                              void* d_out, int out_size, void* d_ws, size_t ws_size,
                              hipStream_t stream) {
    const float* x     = (const float*)d_in[0];
    const float* w_om  = (const float*)d_in[1];
    const float* b_om  = (const float*)d_in[2];
    const float* w_dcn = (const float*)d_in[3];
    float* out = (float*)d_out;

    // workspace layout (77.3 MB total)
    char* ws = (char*)d_ws;
    float*          om   = (float*)(ws);                         // 34,560,000 B
    unsigned short* xT   = (unsigned short*)(ws + 34560000);     // 40,960,000 B
    unsigned short* wom2 = (unsigned short*)(ws + 75520000);     //    589,824 B
    unsigned short* wt2  = (unsigned short*)(ws + 76109824);     //  1,179,648 B

    transpose_x<<<1250, 256, 0, stream>>>(x, xT);
    prep_wom   <<<1152, 256, 0, stream>>>(w_om, wom2);
    prep_wdcn  <<<2304, 256, 0, stream>>>(w_dcn, wt2);
    om_mfma    <<<1250, 256, 0, stream>>>(xT, wom2, b_om, om);
    dcn_mfma   <<<1250, 512, 0, stream>>>(xT, om, wt2, out);
}

// Round 5
// 507.890 us; speedup vs baseline: 6.7418x; 1.2129x over previous
//
#include <hip/hip_runtime.h>
#include <math.h>

// Problem constants
#define HH 200
#define WW 200
#define CIN 256
#define OMCH 108   // 72 offset + 36 mask
#define OCH 256
#define NPIX (HH*WW)

typedef __bf16 bf16x8 __attribute__((ext_vector_type(8)));
typedef float floatx4 __attribute__((ext_vector_type(4)));

static __device__ __forceinline__ unsigned short bf16bits(float v) {
    __bf16 h = (__bf16)v;
    return __builtin_bit_cast(unsigned short, h);
}

// ---------------------------------------------------------------------------
// P0: x [B][C][HW] fp32 -> xT [B][HW][C] bf16.  64-pixel tiles, LDS transpose.
__global__ __launch_bounds__(256) void transpose_x(const float* __restrict__ x,
                                                   unsigned short* __restrict__ xT) {
    __shared__ __align__(16) unsigned short st[64][264];
    int t = threadIdx.x;
    int blk = blockIdx.x;                 // 2 * 625
    int b = blk / 625, pix0 = (blk % 625) * 64;
    const float* xb = x + (size_t)b * CIN * NPIX + pix0;
    int p = t & 63, oct = t >> 6;

    for (int c32 = 0; c32 < CIN; c32 += 32) {
        int c = c32 + oct * 8;
        union { unsigned short u[8]; float4 f; } pk;
#pragma unroll
        for (int i = 0; i < 8; i++)
            pk.u[i] = bf16bits(xb[(size_t)(c + i) * NPIX + p]);
        *(float4*)&st[p][c] = pk.f;
    }
    __syncthreads();
    int p2 = t >> 2, qo = t & 3;
    unsigned short* dst = xT + ((size_t)b * NPIX + pix0 + p2) * CIN + qo * 64;
#pragma unroll
    for (int j = 0; j < 8; j++)
        *(float4*)(dst + j * 8) = *(const float4*)&st[p2][qo * 64 + j * 8];
}

// ---------------------------------------------------------------------------
// P1: w_om [108][256][3][3] fp32 -> wom2 bf16 [128 padded oc][klin], klin = tap*256 + c
__global__ void prep_wom(const float* __restrict__ w, unsigned short* __restrict__ wom2) {
    int i = blockIdx.x * 256 + threadIdx.x;   // i < 128*2304
    int oc = i / 2304, klin = i % 2304;
    int tap = klin >> 8, c = klin & 255;
    float v = (oc < OMCH) ? w[(size_t)oc * 2304 + c * 9 + tap] : 0.f;
    wom2[i] = bf16bits(v);
}

// P2: w_dcn [256][256][3][3] fp32 -> wt2 bf16 [oc][klin], klin = (g*9+k)*64 + c
__global__ void prep_wdcn(const float* __restrict__ w, unsigned short* __restrict__ wt2) {
    int i = blockIdx.x * 256 + threadIdx.x;   // i < 256*2304
    int oc = i / 2304, klin = i % 2304;
    int gk = klin >> 6, c = klin & 63;
    int g = gk / 9, kk = gk % 9;
    wt2[i] = bf16bits(w[(size_t)oc * 2304 + (g * 64 + c) * 9 + kk]);
}

// ---------------------------------------------------------------------------
// K1: om conv via bf16 MFMA, software-pipelined staging, coalesced lane map.
// 256 thr / 4 waves, 64 px/block. Wave wv -> oc [32wv, 32wv+32).
// Staging: thread (p4 = t>>2, c4 = t&3) loads 2x16B of pixel p4's 64-ch slice.
__global__ __launch_bounds__(256, 4) void om_mfma(const unsigned short* __restrict__ xT,
                                                  const unsigned short* __restrict__ wom2,
                                                  const float* __restrict__ bom,
                                                  float* __restrict__ om) {
    __shared__ __align__(16) unsigned short vbuf[2][64][72];  // [p][64c + 8 pad]

    int t = threadIdx.x;
    int p4 = t >> 2;                      // staging pixel 0..63
    int c4 = t & 3;                       // staging chunk 0..3 (16B units)
    int n16 = t & 15, quad = (t & 63) >> 4, wv = t >> 6;
    int ocbase = wv * 32;

    int gp0 = blockIdx.x * 64;            // 1250 blocks
    int b = gp0 / NPIX;
    int pix0 = gp0 - b * NPIX;
    int spix = pix0 + p4;                 // my staging pixel
    int sh = spix / WW, sw = spix % WW;
    const unsigned short* xtb = xT + (size_t)b * NPIX * CIN;

    floatx4 acc[2][4];
#pragma unroll
    for (int i = 0; i < 2; i++)
#pragma unroll
        for (int j = 0; j < 4; j++) acc[i][j] = (floatx4){0.f, 0.f, 0.f, 0.f};

    // stage it=0 (tap 0: di=-1,dj=-1; c0=0)
    {
        int h2 = sh - 1, w2 = sw - 1;
        bool valid = ((unsigned)h2 < (unsigned)HH) && ((unsigned)w2 < (unsigned)WW);
        float4 fa = {0.f,0.f,0.f,0.f}, fb = {0.f,0.f,0.f,0.f};
        if (valid) {
            const unsigned short* src = xtb + (size_t)(h2 * WW + w2) * CIN + c4 * 8;
            fa = *(const float4*)src;
            fb = *(const float4*)(src + 32);
        }
        *(float4*)&vbuf[0][p4][c4 * 8]      = fa;
        *(float4*)&vbuf[0][p4][32 + c4 * 8] = fb;
    }
    __syncthreads();

    for (int it = 0; it < 36; it++) {
        int tap = it >> 2, c0 = (it & 3) << 6;
        int cur = it & 1;
        bool have = (it < 35);

        // --- prefetch next staging chunk into registers ---
        float4 nfa = {0.f,0.f,0.f,0.f}, nfb = {0.f,0.f,0.f,0.f};
        if (have) {
            int itn = it + 1;
            int tapn = itn >> 2, c0n = (itn & 3) << 6;
            int h2 = sh + tapn / 3 - 1, w2 = sw + tapn % 3 - 1;
            bool valid = ((unsigned)h2 < (unsigned)HH) && ((unsigned)w2 < (unsigned)WW);
            if (valid) {
                const unsigned short* src = xtb + (size_t)(h2 * WW + w2) * CIN + c0n + c4 * 8;
                nfa = *(const float4*)src;
                nfb = *(const float4*)(src + 32);
            }
        }

        // --- MFMA phase ---
        const unsigned short* wb = wom2 + (size_t)(tap * 256 + c0) + quad * 8;
#pragma unroll
        for (int ks = 0; ks < 2; ks++) {
            bf16x8 bf0 = *(const bf16x8*)&vbuf[cur][n16     ][ks * 32 + quad * 8];
            bf16x8 bf1 = *(const bf16x8*)&vbuf[cur][16 + n16][ks * 32 + quad * 8];
            bf16x8 bf2 = *(const bf16x8*)&vbuf[cur][32 + n16][ks * 32 + quad * 8];
            bf16x8 bf3 = *(const bf16x8*)&vbuf[cur][48 + n16][ks * 32 + quad * 8];
#pragma unroll
            for (int oi = 0; oi < 2; oi++) {
                bf16x8 a = *(const bf16x8*)&wb[(size_t)(ocbase + oi * 16 + n16) * 2304 + ks * 32];
                acc[oi][0] = __builtin_amdgcn_mfma_f32_16x16x32_bf16(a, bf0, acc[oi][0], 0, 0, 0);
                acc[oi][1] = __builtin_amdgcn_mfma_f32_16x16x32_bf16(a, bf1, acc[oi][1], 0, 0, 0);
                acc[oi][2] = __builtin_amdgcn_mfma_f32_16x16x32_bf16(a, bf2, acc[oi][2], 0, 0, 0);
                acc[oi][3] = __builtin_amdgcn_mfma_f32_16x16x32_bf16(a, bf3, acc[oi][3], 0, 0, 0);
            }
        }

        if (have) {
            *(float4*)&vbuf[cur ^ 1][p4][c4 * 8]      = nfa;
            *(float4*)&vbuf[cur ^ 1][p4][32 + c4 * 8] = nfb;
            __syncthreads();
        }
    }

    // epilogue: D col = n16 (pixel), row = quad*4+r (oc); + bias
#pragma unroll
    for (int oi = 0; oi < 2; oi++) {
        int oc0 = ocbase + oi * 16 + quad * 4;
#pragma unroll
        for (int pt = 0; pt < 4; pt++) {
            int gpix = pix0 + pt * 16 + n16;
#pragma unroll
            for (int r = 0; r < 4; r++) {
                int occ = oc0 + r;
                if (occ < OMCH)
                    om[((size_t)(b * OMCH + occ)) * NPIX + gpix] = acc[oi][pt][r] + bom[occ];
            }
        }
    }
}

// ---------------------------------------------------------------------------
// K2: fused DCN. 512 thr / 8 waves, 64 px/block. Wave wv -> oc [32wv, +32).
// Gather lane map: lane = p8*8 + chunk; 8-lane cluster loads one pixel's
// contiguous 128B group slice per corner. Wave oct samples pixels [8oct, 8oct+8).
__global__ __launch_bounds__(512, 4) void dcn_mfma(const unsigned short* __restrict__ xT,
                                                   const float* __restrict__ om,
                                                   const unsigned short* __restrict__ wt2,
                                                   float* __restrict__ out) {
    __shared__ float4  wPar[36 * 64];                        // 36864 B
    __shared__ ushort4 iPar[36 * 64];                        // 18432 B
    __shared__ __align__(16) unsigned short vbuf[2][64][72]; // 18432 B

    int t = threadIdx.x;
    int l = t & 63;
    int oct = t >> 6;             // wave id
    int p8 = l >> 3;              // pixel sub-index within wave
    int chunk = l & 7;            // 16B channel chunk -> channels chunk*8..+8
    int mypix = oct * 8 + p8;     // staging pixel 0..63
    int n16 = t & 15, quad = l >> 4;
    int ocbase = oct * 32;

    int gp0 = blockIdx.x * 64;    // 1250 blocks
    int b = gp0 / NPIX;
    int pix0 = gp0 - b * NPIX;
    const unsigned short* xtb = xT + (size_t)b * NPIX * CIN;
    const float* omb = om + (size_t)b * OMCH * NPIX;

    // ---- prologue: sampling params for all (gk, p) ----
    for (int r = t; r < 36 * 64; r += 512) {
        int gk = r >> 6, p = r & 63;
        int g = gk / 9, kk = gk % 9;
        int ki = kk / 3, kj = kk % 3;
        int pp = pix0 + p;
        int hh = pp / WW, ww2 = pp % WW;
        float dy = omb[(size_t)(g * 18 + 2 * kk    ) * NPIX + pp];
        float dx = omb[(size_t)(g * 18 + 2 * kk + 1) * NPIX + pp];
        float mr = omb[(size_t)(72 + g * 9 + kk    ) * NPIX + pp];
        float m = 1.f / (1.f + __expf(-mr));
        float py = (float)(hh - 1 + ki) + dy;
        float px = (float)(ww2 - 1 + kj) + dx;
        float fy = floorf(py), fx = floorf(px);
        float wy = py - fy, wx = px - fx;
        int y0 = (int)fy, x0 = (int)fx, y1 = y0 + 1, x1 = x0 + 1;
        bool vy0 = (y0 >= 0) && (y0 < HH), vy1 = (y1 >= 0) && (y1 < HH);
        bool vx0 = (x0 >= 0) && (x0 < WW), vx1 = (x1 >= 0) && (x1 < WW);
        int cy0 = min(max(y0, 0), HH - 1), cy1 = min(max(y1, 0), HH - 1);
        int cx0 = min(max(x0, 0), WW - 1), cx1 = min(max(x1, 0), WW - 1);
        float4 w4;
        w4.x = (vy0 && vx0) ? (1.f - wy) * (1.f - wx) * m : 0.f;
        w4.y = (vy0 && vx1) ? (1.f - wy) * wx * m : 0.f;
        w4.z = (vy1 && vx0) ? wy * (1.f - wx) * m : 0.f;
        w4.w = (vy1 && vx1) ? wy * wx * m : 0.f;
        ushort4 i4;
        i4.x = (unsigned short)(cy0 * WW + cx0);
        i4.y = (unsigned short)(cy0 * WW + cx1);
        i4.z = (unsigned short)(cy1 * WW + cx0);
        i4.w = (unsigned short)(cy1 * WW + cx1);
        wPar[r] = w4;
        iPar[r] = i4;
    }
    __syncthreads();

    floatx4 acc[2][4];
#pragma unroll
    for (int i = 0; i < 2; i++)
#pragma unroll
        for (int j = 0; j < 4; j++) acc[i][j] = (floatx4){0.f, 0.f, 0.f, 0.f};

    // ---- stage gk = 0 ----
    {
        float4 w4 = wPar[mypix];
        ushort4 i4 = iPar[mypix];
        const unsigned short* xg = xtb + chunk * 8;     // g = 0
        bf16x8 c00 = *(const bf16x8*)(xg + (size_t)i4.x * CIN);
        bf16x8 c01 = *(const bf16x8*)(xg + (size_t)i4.y * CIN);
        bf16x8 c10 = *(const bf16x8*)(xg + (size_t)i4.z * CIN);
        bf16x8 c11 = *(const bf16x8*)(xg + (size_t)i4.w * CIN);
        union { unsigned short u[8]; float4 f; } pk;
#pragma unroll
        for (int i = 0; i < 8; i++) {
            float v = w4.x * (float)c00[i] + w4.y * (float)c01[i]
                    + w4.z * (float)c10[i] + w4.w * (float)c11[i];
            pk.u[i] = bf16bits(v);
        }
        *(float4*)&vbuf[0][mypix][chunk * 8] = pk.f;
    }
    __syncthreads();

    for (int gk = 0; gk < 36; gk++) {
        int cur = gk & 1;
        bool have = (gk < 35);

        // --- prefetch gk+1 corner gathers ---
        float4 nw4;
        bf16x8 n00, n01, n10, n11;
        if (have) {
            int gkn = gk + 1;
            nw4 = wPar[gkn * 64 + mypix];
            ushort4 i4 = iPar[gkn * 64 + mypix];
            const unsigned short* xg = xtb + (gkn / 9) * 64 + chunk * 8;
            n00 = *(const bf16x8*)(xg + (size_t)i4.x * CIN);
            n01 = *(const bf16x8*)(xg + (size_t)i4.y * CIN);
            n10 = *(const bf16x8*)(xg + (size_t)i4.z * CIN);
            n11 = *(const bf16x8*)(xg + (size_t)i4.w * CIN);
        }

        // --- MFMA phase ---
        const unsigned short* wb = wt2 + gk * 64 + quad * 8;
#pragma unroll
        for (int ks = 0; ks < 2; ks++) {
            bf16x8 bf0 = *(const bf16x8*)&vbuf[cur][n16     ][ks * 32 + quad * 8];
            bf16x8 bf1 = *(const bf16x8*)&vbuf[cur][16 + n16][ks * 32 + quad * 8];
            bf16x8 bf2 = *(const bf16x8*)&vbuf[cur][32 + n16][ks * 32 + quad * 8];
            bf16x8 bf3 = *(const bf16x8*)&vbuf[cur][48 + n16][ks * 32 + quad * 8];
#pragma unroll
            for (int oi = 0; oi < 2; oi++) {
                bf16x8 a = *(const bf16x8*)&wb[(size_t)(ocbase + oi * 16 + n16) * 2304 + ks * 32];
                acc[oi][0] = __builtin_amdgcn_mfma_f32_16x16x32_bf16(a, bf0, acc[oi][0], 0, 0, 0);
                acc[oi][1] = __builtin_amdgcn_mfma_f32_16x16x32_bf16(a, bf1, acc[oi][1], 0, 0, 0);
                acc[oi][2] = __builtin_amdgcn_mfma_f32_16x16x32_bf16(a, bf2, acc[oi][2], 0, 0, 0);
                acc[oi][3] = __builtin_amdgcn_mfma_f32_16x16x32_bf16(a, bf3, acc[oi][3], 0, 0, 0);
            }
        }

        if (have) {
            union { unsigned short u[8]; float4 f; } pk;
#pragma unroll
            for (int i = 0; i < 8; i++) {
                float v = nw4.x * (float)n00[i] + nw4.y * (float)n01[i]
                        + nw4.z * (float)n10[i] + nw4.w * (float)n11[i];
                pk.u[i] = bf16bits(v);
            }
            *(float4*)&vbuf[cur ^ 1][mypix][chunk * 8] = pk.f;
            __syncthreads();
        }
    }

    // ---- epilogue: ReLU + store ----
#pragma unroll
    for (int oi = 0; oi < 2; oi++)
#pragma unroll
        for (int pt = 0; pt < 4; pt++) {
            int gpix = pix0 + pt * 16 + n16;
#pragma unroll
            for (int r = 0; r < 4; r++) {
                int oc = ocbase + oi * 16 + quad * 4 + r;
                out[((size_t)(b * OCH + oc)) * NPIX + gpix] = fmaxf(acc[oi][pt][r], 0.f);
            }
        }
}

// ---------------------------------------------------------------------------
extern "C" void kernel_launch(void* const* d_in, const int* in_sizes, int n_in,
                              void* d_out, int out_size, void* d_ws, size_t ws_size,
                              hipStream_t stream) {
    const float* x     = (const float*)d_in[0];
    const float* w_om  = (const float*)d_in[1];
    const float* b_om  = (const float*)d_in[2];
    const float* w_dcn = (const float*)d_in[3];
    float* out = (float*)d_out;

    // workspace layout (77.3 MB total)
    char* ws = (char*)d_ws;
    float*          om   = (float*)(ws);                         // 34,560,000 B
    unsigned short* xT   = (unsigned short*)(ws + 34560000);     // 40,960,000 B
    unsigned short* wom2 = (unsigned short*)(ws + 75520000);     //    589,824 B
    unsigned short* wt2  = (unsigned short*)(ws + 76109824);     //  1,179,648 B

    transpose_x<<<1250, 256, 0, stream>>>(x, xT);
    prep_wom   <<<1152, 256, 0, stream>>>(w_om, wom2);
    prep_wdcn  <<<2304, 256, 0, stream>>>(w_dcn, wt2);
    om_mfma    <<<1250, 256, 0, stream>>>(xT, wom2, b_om, om);
    dcn_mfma   <<<1250, 512, 0, stream>>>(xT, om, wt2, out);
}

// Round 6
// 504.093 us; speedup vs baseline: 6.7925x; 1.0075x over previous
//
#include <hip/hip_runtime.h>
#include <math.h>

// Problem constants
#define HH 200
#define WW 200
#define CIN 256
#define OMCH 108   // 72 offset + 36 mask
#define OCH 256
#define NPIX (HH*WW)

typedef __bf16 bf16x8 __attribute__((ext_vector_type(8)));
typedef float floatx4 __attribute__((ext_vector_type(4)));

static __device__ __forceinline__ unsigned short bf16bits(float v) {
    __bf16 h = (__bf16)v;
    return __builtin_bit_cast(unsigned short, h);
}
static __device__ __forceinline__ float lo_bf(unsigned int u) {
    return __builtin_bit_cast(float, u << 16);
}
static __device__ __forceinline__ float hi_bf(unsigned int u) {
    return __builtin_bit_cast(float, u & 0xffff0000u);
}

// ---------------------------------------------------------------------------
// P0: x [B][C][HW] fp32 -> xT [B][HW][C] bf16.  64-pixel tiles, LDS transpose.
__global__ __launch_bounds__(256) void transpose_x(const float* __restrict__ x,
                                                   unsigned short* __restrict__ xT) {
    __shared__ __align__(16) unsigned short st[64][264];
    int t = threadIdx.x;
    int blk = blockIdx.x;                 // 2 * 625
    int b = blk / 625, pix0 = (blk % 625) * 64;
    const float* xb = x + (size_t)b * CIN * NPIX + pix0;
    int p = t & 63, oct = t >> 6;

    for (int c32 = 0; c32 < CIN; c32 += 32) {
        int c = c32 + oct * 8;
        union { unsigned short u[8]; float4 f; } pk;
#pragma unroll
        for (int i = 0; i < 8; i++)
            pk.u[i] = bf16bits(xb[(size_t)(c + i) * NPIX + p]);
        *(float4*)&st[p][c] = pk.f;
    }
    __syncthreads();
    int p2 = t >> 2, qo = t & 3;
    unsigned short* dst = xT + ((size_t)b * NPIX + pix0 + p2) * CIN + qo * 64;
#pragma unroll
    for (int j = 0; j < 8; j++)
        *(float4*)(dst + j * 8) = *(const float4*)&st[p2][qo * 64 + j * 8];
}

// ---------------------------------------------------------------------------
// P1: w_om [108][256][3][3] fp32 -> wom2 bf16 [128 padded oc][klin], klin = tap*256 + c
__global__ void prep_wom(const float* __restrict__ w, unsigned short* __restrict__ wom2) {
    int i = blockIdx.x * 256 + threadIdx.x;   // i < 128*2304
    int oc = i / 2304, klin = i % 2304;
    int tap = klin >> 8, c = klin & 255;
    float v = (oc < OMCH) ? w[(size_t)oc * 2304 + c * 9 + tap] : 0.f;
    wom2[i] = bf16bits(v);
}

// P2: w_dcn [256][256][3][3] fp32 -> wt2 bf16 [oc][klin], klin = (g*9+k)*64 + c
__global__ void prep_wdcn(const float* __restrict__ w, unsigned short* __restrict__ wt2) {
    int i = blockIdx.x * 256 + threadIdx.x;   // i < 256*2304
    int oc = i / 2304, klin = i % 2304;
    int gk = klin >> 6, c = klin & 63;
    int g = gk / 9, kk = gk % 9;
    wt2[i] = bf16bits(w[(size_t)oc * 2304 + (g * 64 + c) * 9 + kk]);
}

// ---------------------------------------------------------------------------
// K1: om conv via bf16 MFMA. 512 thr / 8 waves, 128 px/block.
// Waves: (wv&3) -> oc quarter, (wv>>2) -> pixel half (64 px each).
// 36 iters: tap (9) x 64-ch chunk (4); stage v[64c][128p] from xT, pipelined.
__global__ __launch_bounds__(512, 6) void om_mfma(const unsigned short* __restrict__ xT,
                                                  const unsigned short* __restrict__ wom2,
                                                  const float* __restrict__ bom,
                                                  float* __restrict__ om) {
    __shared__ __align__(16) unsigned short vbuf[2][128][72];  // [p][64c + 8 pad] = 36864 B

    int t = threadIdx.x;
    int p4 = t >> 2;                      // staging pixel 0..127
    int c4 = t & 3;                       // staging chunk 0..3
    int lane = t & 63, n16 = t & 15, quad = lane >> 4, wv = t >> 6;
    int ocbase = (wv & 3) * 32;
    int ph = (wv >> 2) * 64;

    int gp0 = blockIdx.x * 128;           // 625 blocks over 80000 flat pixels
    int sp = gp0 + p4;                    // staging flat pixel (may straddle batch)
    int sb = (sp >= NPIX) ? 1 : 0;
    int srem = sp - sb * NPIX;
    int sh = srem / WW, sw = srem % WW;
    const unsigned short* xtb = xT + (size_t)sb * NPIX * CIN;

    floatx4 acc[2][4];
#pragma unroll
    for (int i = 0; i < 2; i++)
#pragma unroll
        for (int j = 0; j < 4; j++) acc[i][j] = (floatx4){0.f, 0.f, 0.f, 0.f};

    // stage it=0 (tap 0: di=-1,dj=-1; c0=0)
    {
        int h2 = sh - 1, w2 = sw - 1;
        bool valid = ((unsigned)h2 < (unsigned)HH) && ((unsigned)w2 < (unsigned)WW);
        float4 fa = {0.f,0.f,0.f,0.f}, fb = {0.f,0.f,0.f,0.f};
        if (valid) {
            const unsigned short* src = xtb + (size_t)(h2 * WW + w2) * CIN + c4 * 8;
            fa = *(const float4*)src;
            fb = *(const float4*)(src + 32);
        }
        *(float4*)&vbuf[0][p4][c4 * 8]      = fa;
        *(float4*)&vbuf[0][p4][32 + c4 * 8] = fb;
    }
    __syncthreads();

    for (int it = 0; it < 36; it++) {
        int tap = it >> 2, c0 = (it & 3) << 6;
        int cur = it & 1;
        bool have = (it < 35);

        // --- prefetch next staging chunk into registers ---
        float4 nfa = {0.f,0.f,0.f,0.f}, nfb = {0.f,0.f,0.f,0.f};
        if (have) {
            int itn = it + 1;
            int tapn = itn >> 2, c0n = (itn & 3) << 6;
            int h2 = sh + tapn / 3 - 1, w2 = sw + tapn % 3 - 1;
            bool valid = ((unsigned)h2 < (unsigned)HH) && ((unsigned)w2 < (unsigned)WW);
            if (valid) {
                const unsigned short* src = xtb + (size_t)(h2 * WW + w2) * CIN + c0n + c4 * 8;
                nfa = *(const float4*)src;
                nfb = *(const float4*)(src + 32);
            }
        }

        // --- MFMA phase ---
        const unsigned short* wb = wom2 + (size_t)(tap * 256 + c0) + quad * 8;
#pragma unroll
        for (int ks = 0; ks < 2; ks++) {
            bf16x8 bf0 = *(const bf16x8*)&vbuf[cur][ph + n16     ][ks * 32 + quad * 8];
            bf16x8 bf1 = *(const bf16x8*)&vbuf[cur][ph + 16 + n16][ks * 32 + quad * 8];
            bf16x8 bf2 = *(const bf16x8*)&vbuf[cur][ph + 32 + n16][ks * 32 + quad * 8];
            bf16x8 bf3 = *(const bf16x8*)&vbuf[cur][ph + 48 + n16][ks * 32 + quad * 8];
#pragma unroll
            for (int oi = 0; oi < 2; oi++) {
                bf16x8 a = *(const bf16x8*)&wb[(size_t)(ocbase + oi * 16 + n16) * 2304 + ks * 32];
                acc[oi][0] = __builtin_amdgcn_mfma_f32_16x16x32_bf16(a, bf0, acc[oi][0], 0, 0, 0);
                acc[oi][1] = __builtin_amdgcn_mfma_f32_16x16x32_bf16(a, bf1, acc[oi][1], 0, 0, 0);
                acc[oi][2] = __builtin_amdgcn_mfma_f32_16x16x32_bf16(a, bf2, acc[oi][2], 0, 0, 0);
                acc[oi][3] = __builtin_amdgcn_mfma_f32_16x16x32_bf16(a, bf3, acc[oi][3], 0, 0, 0);
            }
        }

        if (have) {
            *(float4*)&vbuf[cur ^ 1][p4][c4 * 8]      = nfa;
            *(float4*)&vbuf[cur ^ 1][p4][32 + c4 * 8] = nfb;
            __syncthreads();
        }
    }

    // epilogue: D col = n16 (pixel), row = quad*4+r (oc); + bias
#pragma unroll
    for (int oi = 0; oi < 2; oi++) {
        int oc0 = ocbase + oi * 16 + quad * 4;
        if (oc0 < OMCH) {
#pragma unroll
            for (int pt = 0; pt < 4; pt++) {
                int fp = gp0 + ph + pt * 16 + n16;
                int bq = (fp >= NPIX) ? 1 : 0;
                int rem = fp - bq * NPIX;
#pragma unroll
                for (int r = 0; r < 4; r++) {
                    int occ = oc0 + r;
                    if (occ < OMCH)
                        om[((size_t)(bq * OMCH + occ)) * NPIX + rem] = acc[oi][pt][r] + bom[occ];
                }
            }
        }
    }
}

// ---------------------------------------------------------------------------
// K2: fused DCN. 512 thr / 8 waves, 64 px/block. Wave wv -> oc [32wv, +32).
// Params packed to 12 B/record in LDS (46 KB total -> 3 blocks/CU).
// Pipeline: parm(gk+2) LDS-read || gather(gk+1) || MFMA(gk) || pack(gk+1).
__global__ __launch_bounds__(512, 6) void dcn_mfma(const unsigned short* __restrict__ xT,
                                                   const float* __restrict__ om,
                                                   const unsigned short* __restrict__ wt2,
                                                   float* __restrict__ out) {
    __shared__ unsigned int iPk[36 * 64];                    //  9216 B: i00 | dx1<<16 | dy1<<17
    __shared__ uint2        wPk[36 * 64];                    // 18432 B: 4 x bf16 corner weights
    __shared__ __align__(16) unsigned short vbuf[2][64][72]; // 18432 B

    int t = threadIdx.x;
    int l = t & 63;
    int oct = t >> 6;             // wave id
    int p8 = l >> 3;              // pixel sub-index within wave
    int chunk = l & 7;            // 16B channel chunk
    int mypix = oct * 8 + p8;     // staging pixel 0..63
    int n16 = t & 15, quad = l >> 4;
    int ocbase = oct * 32;

    int gp0 = blockIdx.x * 64;    // 1250 blocks; 40000 % 64 == 0, no batch straddle
    int b = gp0 / NPIX;
    int pix0 = gp0 - b * NPIX;
    const unsigned short* xtb = xT + (size_t)b * NPIX * CIN;
    const float* omb = om + (size_t)b * OMCH * NPIX;

    // ---- prologue: packed sampling params for all (gk, p) ----
    for (int r = t; r < 36 * 64; r += 512) {
        int gk = r >> 6, p = r & 63;
        int g = gk / 9, kk = gk % 9;
        int ki = kk / 3, kj = kk % 3;
        int pp = pix0 + p;
        int hh = pp / WW, ww2 = pp % WW;
        float dy = omb[(size_t)(g * 18 + 2 * kk    ) * NPIX + pp];
        float dx = omb[(size_t)(g * 18 + 2 * kk + 1) * NPIX + pp];
        float mr = omb[(size_t)(72 + g * 9 + kk    ) * NPIX + pp];
        float m = 1.f / (1.f + __expf(-mr));
        float py = (float)(hh - 1 + ki) + dy;
        float px = (float)(ww2 - 1 + kj) + dx;
        float fy = floorf(py), fx = floorf(px);
        float wy = py - fy, wx = px - fx;
        int y0 = (int)fy, x0 = (int)fx, y1 = y0 + 1, x1 = x0 + 1;
        bool vy0 = (y0 >= 0) && (y0 < HH), vy1 = (y1 >= 0) && (y1 < HH);
        bool vx0 = (x0 >= 0) && (x0 < WW), vx1 = (x1 >= 0) && (x1 < WW);
        int cy0 = min(max(y0, 0), HH - 1), cy1 = min(max(y1, 0), HH - 1);
        int cx0 = min(max(x0, 0), WW - 1), cx1 = min(max(x1, 0), WW - 1);
        float w00 = (vy0 && vx0) ? (1.f - wy) * (1.f - wx) * m : 0.f;
        float w01 = (vy0 && vx1) ? (1.f - wy) * wx * m : 0.f;
        float w10 = (vy1 && vx0) ? wy * (1.f - wx) * m : 0.f;
        float w11 = (vy1 && vx1) ? wy * wx * m : 0.f;
        int i00 = cy0 * WW + cx0;
        unsigned int dx1 = (unsigned int)(cx1 - cx0);   // 0/1
        unsigned int dy1 = (unsigned int)(cy1 - cy0);   // 0/1
        iPk[r] = (unsigned int)i00 | (dx1 << 16) | (dy1 << 17);
        uint2 wp;
        wp.x = (unsigned int)bf16bits(w00) | ((unsigned int)bf16bits(w01) << 16);
        wp.y = (unsigned int)bf16bits(w10) | ((unsigned int)bf16bits(w11) << 16);
        wPk[r] = wp;
    }
    __syncthreads();

    floatx4 acc[2][4];
#pragma unroll
    for (int i = 0; i < 2; i++)
#pragma unroll
        for (int j = 0; j < 4; j++) acc[i][j] = (floatx4){0.f, 0.f, 0.f, 0.f};

    unsigned int ipNext; uint2 wpNext;   // params for the NEXT gather iteration

    // ---- stage gk = 0 (and preload parm(1)) ----
    {
        unsigned int ip = iPk[mypix];
        uint2 wp = wPk[mypix];
        int i00 = ip & 0xffff;
        int dx1 = (ip >> 16) & 1, dy1 = (ip >> 17) & 1;
        int i01 = i00 + dx1, i10 = i00 + dy1 * WW, i11 = i10 + dx1;
        const unsigned short* xg = xtb + chunk * 8;     // g = 0
        bf16x8 c00 = *(const bf16x8*)(xg + (size_t)i00 * CIN);
        bf16x8 c01 = *(const bf16x8*)(xg + (size_t)i01 * CIN);
        bf16x8 c10 = *(const bf16x8*)(xg + (size_t)i10 * CIN);
        bf16x8 c11 = *(const bf16x8*)(xg + (size_t)i11 * CIN);
        ipNext = iPk[64 + mypix];
        wpNext = wPk[64 + mypix];
        float w00 = lo_bf(wp.x), w01 = hi_bf(wp.x);
        float w10 = lo_bf(wp.y), w11 = hi_bf(wp.y);
        union { unsigned short u[8]; float4 f; } pk;
#pragma unroll
        for (int i = 0; i < 8; i++) {
            float v = w00 * (float)c00[i] + w01 * (float)c01[i]
                    + w10 * (float)c10[i] + w11 * (float)c11[i];
            pk.u[i] = bf16bits(v);
        }
        *(float4*)&vbuf[0][mypix][chunk * 8] = pk.f;
    }
    __syncthreads();

    for (int gk = 0; gk < 36; gk++) {
        int cur = gk & 1;
        bool have = (gk < 35);

        // --- gather gk+1 using pre-loaded params (addresses register-ready) ---
        float nw00, nw01, nw10, nw11;
        bf16x8 n00, n01, n10, n11;
        if (have) {
            unsigned int ip = ipNext; uint2 wp = wpNext;
            int i00 = ip & 0xffff;
            int dx1 = (ip >> 16) & 1, dy1 = (ip >> 17) & 1;
            int i01 = i00 + dx1, i10 = i00 + dy1 * WW, i11 = i10 + dx1;
            const unsigned short* xg = xtb + ((gk + 1) / 9) * 64 + chunk * 8;
            n00 = *(const bf16x8*)(xg + (size_t)i00 * CIN);
            n01 = *(const bf16x8*)(xg + (size_t)i01 * CIN);
            n10 = *(const bf16x8*)(xg + (size_t)i10 * CIN);
            n11 = *(const bf16x8*)(xg + (size_t)i11 * CIN);
            nw00 = lo_bf(wp.x); nw01 = hi_bf(wp.x);
            nw10 = lo_bf(wp.y); nw11 = hi_bf(wp.y);
        }
        // --- preload params for gk+2 (decoupled from next iter's gather) ---
        if (gk < 34) {
            ipNext = iPk[(gk + 2) * 64 + mypix];
            wpNext = wPk[(gk + 2) * 64 + mypix];
        }

        // --- MFMA phase (gk) ---
        const unsigned short* wb = wt2 + gk * 64 + quad * 8;
#pragma unroll
        for (int ks = 0; ks < 2; ks++) {
            bf16x8 bf0 = *(const bf16x8*)&vbuf[cur][n16     ][ks * 32 + quad * 8];
            bf16x8 bf1 = *(const bf16x8*)&vbuf[cur][16 + n16][ks * 32 + quad * 8];
            bf16x8 bf2 = *(const bf16x8*)&vbuf[cur][32 + n16][ks * 32 + quad * 8];
            bf16x8 bf3 = *(const bf16x8*)&vbuf[cur][48 + n16][ks * 32 + quad * 8];
#pragma unroll
            for (int oi = 0; oi < 2; oi++) {
                bf16x8 a = *(const bf16x8*)&wb[(size_t)(ocbase + oi * 16 + n16) * 2304 + ks * 32];
                acc[oi][0] = __builtin_amdgcn_mfma_f32_16x16x32_bf16(a, bf0, acc[oi][0], 0, 0, 0);
                acc[oi][1] = __builtin_amdgcn_mfma_f32_16x16x32_bf16(a, bf1, acc[oi][1], 0, 0, 0);
                acc[oi][2] = __builtin_amdgcn_mfma_f32_16x16x32_bf16(a, bf2, acc[oi][2], 0, 0, 0);
                acc[oi][3] = __builtin_amdgcn_mfma_f32_16x16x32_bf16(a, bf3, acc[oi][3], 0, 0, 0);
            }
        }

        if (have) {
            union { unsigned short u[8]; float4 f; } pk;
#pragma unroll
            for (int i = 0; i < 8; i++) {
                float v = nw00 * (float)n00[i] + nw01 * (float)n01[i]
                        + nw10 * (float)n10[i] + nw11 * (float)n11[i];
                pk.u[i] = bf16bits(v);
            }
            *(float4*)&vbuf[cur ^ 1][mypix][chunk * 8] = pk.f;
            __syncthreads();
        }
    }

    // ---- epilogue: ReLU + store ----
#pragma unroll
    for (int oi = 0; oi < 2; oi++)
#pragma unroll
        for (int pt = 0; pt < 4; pt++) {
            int gpix = pix0 + pt * 16 + n16;
#pragma unroll
            for (int r = 0; r < 4; r++) {
                int oc = ocbase + oi * 16 + quad * 4 + r;
                out[((size_t)(b * OCH + oc)) * NPIX + gpix] = fmaxf(acc[oi][pt][r], 0.f);
            }
        }
}

// ---------------------------------------------------------------------------
extern "C" void kernel_launch(void* const* d_in, const int* in_sizes, int n_in,
                              void* d_out, int out_size, void* d_ws, size_t ws_size,
                              hipStream_t stream) {
    const float* x     = (const float*)d_in[0];
    const float* w_om  = (const float*)d_in[1];
    const float* b_om  = (const float*)d_in[2];
    const float* w_dcn = (const float*)d_in[3];
    float* out = (float*)d_out;

    // workspace layout (77.3 MB total)
    char* ws = (char*)d_ws;
    float*          om   = (float*)(ws);                         // 34,560,000 B
    unsigned short* xT   = (unsigned short*)(ws + 34560000);     // 40,960,000 B
    unsigned short* wom2 = (unsigned short*)(ws + 75520000);     //    589,824 B
    unsigned short* wt2  = (unsigned short*)(ws + 76109824);     //  1,179,648 B

    transpose_x<<<1250, 256, 0, stream>>>(x, xT);
    prep_wom   <<<1152, 256, 0, stream>>>(w_om, wom2);
    prep_wdcn  <<<2304, 256, 0, stream>>>(w_dcn, wt2);
    om_mfma    <<< 625, 512, 0, stream>>>(xT, wom2, b_om, om);
    dcn_mfma   <<<1250, 512, 0, stream>>>(xT, om, wt2, out);
}